// Round 1
// baseline (3382.133 us; speedup 1.0000x reference)
//
#include <hip/hip_runtime.h>
#include <cstddef>

#define NN 200000

__device__ __forceinline__ float sigm(float v) { return 1.0f / (1.0f + expf(-v)); }

// ---------------------------------------------------------------------------
// Stage 1 ("child" kernel): for children k in [cs, ce), compute
//   f_k = sigmoid(x[parent(k)] @ W_f + h[k] @ U_f + b_f)
// and reduce over each sibling group (8 consecutive children, thread-owned):
//   fc[parent] = sum f_k * c[k],  ht[parent] = sum h[k]
// Tile: 32 child-rows x 64 dims, K = 512 (256 x-part + 256 h-part).
// ---------------------------------------------------------------------------
__launch_bounds__(256)
__global__ void tree_child_kernel(const float* __restrict__ x,
                                  const float* __restrict__ W_f,
                                  const float* __restrict__ U_f,
                                  const float* __restrict__ b_f,
                                  const float* __restrict__ c,
                                  const float* __restrict__ h,
                                  float* __restrict__ fc,
                                  float* __restrict__ ht,
                                  int cs, int ce, int ps)
{
    __shared__ float As[32][33];   // As[k][row], padded
    __shared__ float Bs[32][64];

    const int t     = threadIdx.x;
    const int col   = t & 63;
    const int r0    = (t >> 6) << 3;       // 8 rows per thread = one sibling group
    const int cBase = cs + blockIdx.x * 32;
    const int dBase = blockIdx.y * 64;

    const int lr = t >> 3;                 // load row 0..31
    const int lk = (t & 7) << 2;           // load k offset 0,4,..,28

    float acc[8];
#pragma unroll
    for (int j = 0; j < 8; ++j) acc[j] = 0.0f;

    for (int k0 = 0; k0 < 512; k0 += 32) {
        // global loads first (latency overlap)
        int k = cBase + lr;
        float4 av = make_float4(0.f, 0.f, 0.f, 0.f);
        if (k < ce) {
            if (k0 < 256) {
                int p = (k - 1) >> 3;
                av = *reinterpret_cast<const float4*>(&x[p * 256 + k0 + lk]);
            } else {
                av = *reinterpret_cast<const float4*>(&h[k * 256 + (k0 - 256) + lk]);
            }
        }
        float bv[8];
#pragma unroll
        for (int i = 0; i < 8; ++i) {
            int idx = t + i * 256;
            int kB  = idx >> 6;
            int cc  = idx & 63;
            bv[i] = (k0 < 256) ? W_f[(k0 + kB) * 256 + dBase + cc]
                               : U_f[(k0 - 256 + kB) * 256 + dBase + cc];
        }
        __syncthreads();
        As[lk + 0][lr] = av.x;
        As[lk + 1][lr] = av.y;
        As[lk + 2][lr] = av.z;
        As[lk + 3][lr] = av.w;
#pragma unroll
        for (int i = 0; i < 8; ++i) {
            (&Bs[0][0])[t + i * 256] = bv[i];
        }
        __syncthreads();
#pragma unroll
        for (int kk = 0; kk < 32; ++kk) {
            float b = Bs[kk][col];
#pragma unroll
            for (int j = 0; j < 8; ++j)
                acc[j] = fmaf(As[kk][r0 + j], b, acc[j]);
        }
    }

    // epilogue: per-thread sibling-group reduction (no atomics)
    int g0 = cBase + r0;                   // first child of this thread's group
    if (g0 < ce) {
        int d = dBase + col;
        float bb  = b_f[d];
        float fcs = 0.f, hts = 0.f;
#pragma unroll
        for (int j = 0; j < 8; ++j) {
            int k = g0 + j;
            if (k < ce) {
                float f = sigm(acc[j] + bb);
                fcs = fmaf(f, c[k * 256 + d], fcs);
                hts += h[k * 256 + d];
            }
        }
        int pl = ((g0 - 1) >> 3) - ps;     // parent-local index within level
        fc[pl * 256 + d] = fcs;
        ht[pl * 256 + d] = hts;
    }
}

// ---------------------------------------------------------------------------
// Stage 2 ("parent" kernel): for parents p in [ps, pe), compute
//   iou = x[p] @ W_iou + ht[p] @ U_iou + b_iou       (3 gates of 256 each)
//   c[p] = sigm(i)*tanh(u) + fc[p];  h[p] = sigm(o)*tanh(c[p])
// Tile: 32 rows x 64 dims x 3 gates, K = 512 (or 256 for leaves).
// ---------------------------------------------------------------------------
template<bool USE_HT>
__launch_bounds__(256)
__global__ void tree_parent_kernel(const float* __restrict__ x,
                                   const float* __restrict__ W_iou,
                                   const float* __restrict__ U_iou,
                                   const float* __restrict__ b_iou,
                                   const float* __restrict__ fc,
                                   const float* __restrict__ ht,
                                   float* __restrict__ c,
                                   float* __restrict__ h,
                                   int ps, int pe)
{
    __shared__ float As[32][33];       // As[k][row]
    __shared__ float Bs[3][32][64];    // per-gate B tiles

    const int t     = threadIdx.x;
    const int col   = t & 63;
    const int r0    = (t >> 6) << 3;
    const int mBase = ps + blockIdx.x * 32;
    const int dBase = blockIdx.y * 64;

    const int lr = t >> 3;
    const int lk = (t & 7) << 2;

    float acc[3][8];
#pragma unroll
    for (int g = 0; g < 3; ++g)
#pragma unroll
        for (int j = 0; j < 8; ++j) acc[g][j] = 0.0f;

    const int KTOT = USE_HT ? 512 : 256;
    for (int k0 = 0; k0 < KTOT; k0 += 32) {
        int node = mBase + lr;
        float4 av = make_float4(0.f, 0.f, 0.f, 0.f);
        if (node < pe) {
            if (k0 < 256) {
                av = *reinterpret_cast<const float4*>(&x[node * 256 + k0 + lk]);
            } else if (8 * node + 1 < NN) {   // only parents with children have ht
                av = *reinterpret_cast<const float4*>(&ht[(node - ps) * 256 + (k0 - 256) + lk]);
            }
        }
        float bv[24];
#pragma unroll
        for (int i = 0; i < 24; ++i) {
            int idx = t + i * 256;
            int g   = idx >> 11;
            int kB  = (idx >> 6) & 31;
            int cc  = idx & 63;
            bv[i] = (k0 < 256) ? W_iou[(k0 + kB) * 768 + g * 256 + dBase + cc]
                               : U_iou[(k0 - 256 + kB) * 768 + g * 256 + dBase + cc];
        }
        __syncthreads();
        As[lk + 0][lr] = av.x;
        As[lk + 1][lr] = av.y;
        As[lk + 2][lr] = av.z;
        As[lk + 3][lr] = av.w;
#pragma unroll
        for (int i = 0; i < 24; ++i) {
            (&Bs[0][0][0])[t + i * 256] = bv[i];
        }
        __syncthreads();
#pragma unroll
        for (int kk = 0; kk < 32; ++kk) {
            float b0 = Bs[0][kk][col];
            float b1 = Bs[1][kk][col];
            float b2 = Bs[2][kk][col];
#pragma unroll
            for (int j = 0; j < 8; ++j) {
                float a = As[kk][r0 + j];
                acc[0][j] = fmaf(a, b0, acc[0][j]);
                acc[1][j] = fmaf(a, b1, acc[1][j]);
                acc[2][j] = fmaf(a, b2, acc[2][j]);
            }
        }
    }

    // fused LSTM epilogue
    int d = dBase + col;
    float bi = b_iou[d];
    float bo = b_iou[256 + d];
    float bu = b_iou[512 + d];
#pragma unroll
    for (int j = 0; j < 8; ++j) {
        int node = mBase + r0 + j;
        if (node < pe) {
            float ig = acc[0][j] + bi;
            float og = acc[1][j] + bo;
            float ug = acc[2][j] + bu;
            float fcv = 0.f;
            if (USE_HT && (8 * node + 1 < NN))
                fcv = fc[(node - ps) * 256 + d];
            float cn = sigm(ig) * tanhf(ug) + fcv;
            float hn = sigm(og) * tanhf(cn);
            c[node * 256 + d] = cn;
            h[node * 256 + d] = hn;
        }
    }
}

// ---------------------------------------------------------------------------

extern "C" void kernel_launch(void* const* d_in, const int* in_sizes, int n_in,
                              void* d_out, int out_size, void* d_ws, size_t ws_size,
                              hipStream_t stream)
{
    const float* x     = (const float*)d_in[0];
    const float* W_iou = (const float*)d_in[1];
    const float* U_iou = (const float*)d_in[2];
    const float* b_iou = (const float*)d_in[3];
    const float* W_f   = (const float*)d_in[4];
    const float* U_f   = (const float*)d_in[5];
    const float* b_f   = (const float*)d_in[6];
    // d_in[7] = parent_idx, d_in[8] = level, d_in[9] = num_levels: structure is
    // implied by the complete 8-ary tree, so these are not needed on device.

    float* h  = (float*)d_out;                       // N x 256 output
    float* c  = (float*)d_ws;                        // N x 256 cell state
    float* fc = c + (size_t)NN * 256;                // <=20320 x 256 per level
    float* ht = fc + (size_t)20320 * 256;            // <=20320 x 256 per level

    // level start indices for the complete 8-ary tree over 200000 nodes
    const int S[8] = {0, 1, 9, 73, 585, 4681, 37449, 200000};

    for (int l = 6; l >= 0; --l) {
        int ps = S[l];
        int pe = S[l + 1];
        int pblk = (pe - ps + 31) / 32;
        if (l < 6) {
            int cs = S[l + 1];
            int ce = S[l + 2];
            int nblk = (ce - cs + 31) / 32;
            tree_child_kernel<<<dim3(nblk, 4), 256, 0, stream>>>(
                x, W_f, U_f, b_f, c, h, fc, ht, cs, ce, ps);
            tree_parent_kernel<true><<<dim3(pblk, 4), 256, 0, stream>>>(
                x, W_iou, U_iou, b_iou, fc, ht, c, h, ps, pe);
        } else {
            tree_parent_kernel<false><<<dim3(pblk, 4), 256, 0, stream>>>(
                x, W_iou, U_iou, b_iou, nullptr, nullptr, c, h, ps, pe);
        }
    }
}

// Round 2
// 1460.843 us; speedup vs baseline: 2.3152x; 2.3152x over previous
//
#include <hip/hip_runtime.h>
#include <cstddef>
#include <cstdint>

#define NN 200000

typedef unsigned short ushort_t;
typedef __attribute__((ext_vector_type(8))) short bf16x8;
typedef __attribute__((ext_vector_type(4))) float f32x4;

#define MFMA(a, b, c) __builtin_amdgcn_mfma_f32_16x16x32_bf16((a), (b), (c), 0, 0, 0)

__device__ __forceinline__ float sigm(float v) { return 1.0f / (1.0f + expf(-v)); }

__device__ __forceinline__ ushort_t bf16_rne(float v) {
    uint32_t u = __float_as_uint(v);
    uint32_t r = u + 0x7FFFu + ((u >> 16) & 1u);
    return (ushort_t)(r >> 16);
}
__device__ __forceinline__ float bf16_tof(ushort_t s) {
    return __uint_as_float(((uint32_t)s) << 16);
}
__device__ __forceinline__ void split3(float v, ushort_t& h, ushort_t& m, ushort_t& l) {
    h = bf16_rne(v); float r1 = v - bf16_tof(h);
    m = bf16_rne(r1); float r2 = r1 - bf16_tof(m);
    l = bf16_rne(r2);
}

union U4 { uint4 u; ushort_t s[8]; };

// ---------------------------------------------------------------------------
// Pre-split a fp32 weight matrix [K][N] into 3 bf16 components stored in
// MFMA-B-fragment layout: elem (k,n) -> ((k>>3)*N + n)*8 + (k&7).
// ---------------------------------------------------------------------------
__global__ void split_weights(const float* __restrict__ src,
                              ushort_t* __restrict__ dh,
                              ushort_t* __restrict__ dm,
                              ushort_t* __restrict__ dl,
                              int K, int N)
{
    int e = blockIdx.x * 256 + threadIdx.x;
    if (e >= K * N) return;
    int k = e / N, n = e - k * N;
    ushort_t h, m, l;
    split3(src[e], h, m, l);
    int o = ((k >> 3) * N + n) * 8 + (k & 7);
    dh[o] = h; dm[o] = m; dl[o] = l;
}

// ---------------------------------------------------------------------------
// Child kernel: F = sigmoid(x[parent] @ W_f + h @ U_f + b_f) for a 128-child
// tile, emulated-fp32 via 6 bf16 MFMA products; epilogue reduces sibling
// groups (8 consecutive children) into fc = sum f*c, ht = sum h.
// Block tile 128 x 128 (blockIdx.y in {0,1} covers d 0..255), K = 512.
// ---------------------------------------------------------------------------
__launch_bounds__(256, 2)
__global__ void tree_child_mfma(const float* __restrict__ x,
                                const ushort_t* __restrict__ wf3,  // 3 x 65536, frag layout
                                const ushort_t* __restrict__ uf3,
                                const float* __restrict__ b_f,
                                const float* __restrict__ cS,
                                const float* __restrict__ hS,
                                float* __restrict__ fc,
                                float* __restrict__ ht,
                                int cs, int ce, int ps)
{
    __shared__ ushort_t As[3][4][128][8];   // 24 KB  [comp][kb][row][i]
    __shared__ ushort_t Bs[3][4][128][8];   // 24 KB  [comp][kb][col][i]

    const int t    = threadIdx.x;
    const int lane = t & 63;
    const int wid  = t >> 6;
    const int wr   = wid >> 1, wc = wid & 1;   // wave = 64 rows x 64 cols
    const int c15  = lane & 15, q = lane >> 4;
    const int cBase = cs + blockIdx.x * 128;
    const int dBase = blockIdx.y * 128;

    f32x4 acc[4][4];
#pragma unroll
    for (int m = 0; m < 4; ++m)
#pragma unroll
        for (int n = 0; n < 4; ++n) acc[m][n] = (f32x4){0.f, 0.f, 0.f, 0.f};

    const int ar  = t >> 1;           // staging row 0..127
    const int aks = (t & 1) * 16;     // staging k offset within 32-step

    for (int k0 = 0; k0 < 512; k0 += 32) {
        // ---- stage A (fp32 -> 3-way bf16 split) ----
        int child = cBase + ar;
        float va[16];
#pragma unroll
        for (int i = 0; i < 16; ++i) va[i] = 0.f;
        if (child < ce) {
            const float* srcp;
            if (k0 < 256) srcp = x  + (size_t)((child - 1) >> 3) * 256 + k0 + aks;
            else          srcp = hS + (size_t)child * 256 + (k0 - 256) + aks;
#pragma unroll
            for (int i = 0; i < 16; i += 4) {
                float4 f = *(const float4*)(srcp + i);
                va[i + 0] = f.x; va[i + 1] = f.y; va[i + 2] = f.z; va[i + 3] = f.w;
            }
        }
#pragma unroll
        for (int hb = 0; hb < 2; ++hb) {
            U4 ph, pm, pl;
#pragma unroll
            for (int i2 = 0; i2 < 8; ++i2) {
                ushort_t hh, mm, ll;
                split3(va[hb * 8 + i2], hh, mm, ll);
                ph.s[i2] = hh; pm.s[i2] = mm; pl.s[i2] = ll;
            }
            int kb = (aks >> 3) + hb;
            *(uint4*)&As[0][kb][ar][0] = ph.u;
            *(uint4*)&As[1][kb][ar][0] = pm.u;
            *(uint4*)&As[2][kb][ar][0] = pl.u;
        }
        // ---- stage B (pre-split weights, contiguous 16B copies) ----
        {
            const ushort_t* wsrc = (k0 < 256) ? wf3 : uf3;
            int kb0 = (k0 & 255) >> 3;
#pragma unroll
            for (int j = 0; j < 6; ++j) {
                int flat = j * 256 + t;
                int comp = flat >> 9, rem = flat & 511;
                int kb = rem >> 7, n = rem & 127;
                const uint4* s = (const uint4*)(wsrc + (size_t)comp * 65536
                                 + ((size_t)(kb0 + kb) * 256 + dBase + n) * 8);
                *(uint4*)&Bs[comp][kb][n][0] = *s;
            }
        }
        __syncthreads();
        // ---- compute: 6-product emulated fp32 ----
        bf16x8 a[4][3];
#pragma unroll
        for (int m = 0; m < 4; ++m) {
            int row = wr * 64 + m * 16 + c15;
#pragma unroll
            for (int cc = 0; cc < 3; ++cc)
                a[m][cc] = *(const bf16x8*)&As[cc][q][row][0];
        }
#pragma unroll
        for (int n = 0; n < 4; ++n) {
            int col = wc * 64 + n * 16 + c15;
            bf16x8 bh = *(const bf16x8*)&Bs[0][q][col][0];
            bf16x8 bm = *(const bf16x8*)&Bs[1][q][col][0];
            bf16x8 bl = *(const bf16x8*)&Bs[2][q][col][0];
#pragma unroll
            for (int m = 0; m < 4; ++m) {
                f32x4 acc_ = acc[m][n];
                acc_ = MFMA(a[m][0], bh, acc_);
                acc_ = MFMA(a[m][1], bh, acc_);
                acc_ = MFMA(a[m][2], bh, acc_);
                acc_ = MFMA(a[m][0], bm, acc_);
                acc_ = MFMA(a[m][1], bm, acc_);
                acc_ = MFMA(a[m][0], bl, acc_);
                acc[m][n] = acc_;
            }
        }
        __syncthreads();
    }

    // ---- epilogue: sibling-group reduction, no atomics ----
#pragma unroll
    for (int n = 0; n < 4; ++n) {
        int d = dBase + wc * 64 + n * 16 + c15;
        float bfv = b_f[d];
#pragma unroll
        for (int m = 0; m < 4; ++m) {
            float fcs = 0.f, hts = 0.f;
#pragma unroll
            for (int j = 0; j < 4; ++j) {
                int row   = wr * 64 + m * 16 + q * 4 + j;
                int child = cBase + row;
                if (child < ce) {
                    float f = sigm(acc[m][n][j] + bfv);
                    fcs = fmaf(f, cS[(size_t)child * 256 + d], fcs);
                    hts += hS[(size_t)child * 256 + d];
                }
            }
            fcs += __shfl_xor(fcs, 16);
            hts += __shfl_xor(hts, 16);
            if ((q & 1) == 0) {
                int child0 = cBase + wr * 64 + m * 16 + (q >> 1) * 8;
                if (child0 < ce) {
                    int pl_ = ((child0 - 1) >> 3) - ps;
                    fc[(size_t)pl_ * 256 + d] = fcs;
                    ht[(size_t)pl_ * 256 + d] = hts;
                }
            }
        }
    }
}

// ---------------------------------------------------------------------------
// Parent kernel: iou = x @ W_iou + ht @ U_iou + b_iou for a 128-row tile,
// 3 gates x 64 d per block (blockIdx.y in 0..3). The (i,o,u) triple for a
// given (row, d) lands in the same lane (n-frags 4 apart) -> in-register
// LSTM epilogue writing c and h.
// ---------------------------------------------------------------------------
template<bool USE_HT>
__launch_bounds__(256, 2)
__global__ void tree_parent_mfma(const float* __restrict__ x,
                                 const ushort_t* __restrict__ wiou3,  // 3 x 196608, frag layout
                                 const ushort_t* __restrict__ uiou3,
                                 const float* __restrict__ b_iou,
                                 const float* __restrict__ fcR,
                                 const float* __restrict__ htR,
                                 float* __restrict__ cW,
                                 float* __restrict__ hW,
                                 int ps, int pe)
{
    __shared__ ushort_t As[3][4][128][8];   // 24 KB
    __shared__ ushort_t Bs[3][4][192][8];   // 36 KB

    const int t    = threadIdx.x;
    const int lane = t & 63;
    const int w    = t >> 6;                 // wave: 32 rows x 192 cols
    const int c15  = lane & 15, q = lane >> 4;
    const int pBase = ps + blockIdx.x * 128;
    const int dBase = blockIdx.y * 64;

    f32x4 acc[2][12];
#pragma unroll
    for (int m = 0; m < 2; ++m)
#pragma unroll
        for (int n = 0; n < 12; ++n) acc[m][n] = (f32x4){0.f, 0.f, 0.f, 0.f};

    const int ar  = t >> 1;
    const int aks = (t & 1) * 16;
    const int KTOT = USE_HT ? 512 : 256;

    for (int k0 = 0; k0 < KTOT; k0 += 32) {
        // ---- stage A ----
        int node = pBase + ar;
        float va[16];
#pragma unroll
        for (int i = 0; i < 16; ++i) va[i] = 0.f;
        if (node < pe) {
            const float* srcp = nullptr;
            if (k0 < 256) srcp = x + (size_t)node * 256 + k0 + aks;
            else if (USE_HT && node <= 24999) srcp = htR + (size_t)(node - ps) * 256 + (k0 - 256) + aks;
            if (srcp) {
#pragma unroll
                for (int i = 0; i < 16; i += 4) {
                    float4 f = *(const float4*)(srcp + i);
                    va[i + 0] = f.x; va[i + 1] = f.y; va[i + 2] = f.z; va[i + 3] = f.w;
                }
            }
        }
#pragma unroll
        for (int hb = 0; hb < 2; ++hb) {
            U4 ph, pm, pl;
#pragma unroll
            for (int i2 = 0; i2 < 8; ++i2) {
                ushort_t hh, mm, ll;
                split3(va[hb * 8 + i2], hh, mm, ll);
                ph.s[i2] = hh; pm.s[i2] = mm; pl.s[i2] = ll;
            }
            int kb = (aks >> 3) + hb;
            *(uint4*)&As[0][kb][ar][0] = ph.u;
            *(uint4*)&As[1][kb][ar][0] = pm.u;
            *(uint4*)&As[2][kb][ar][0] = pl.u;
        }
        // ---- stage B: 3 comps x 4 kb x 192 cols (gate-major) ----
        {
            const ushort_t* wsrc = (k0 < 256) ? wiou3 : uiou3;
            int kb0 = (k0 & 255) >> 3;
#pragma unroll
            for (int comp = 0; comp < 3; ++comp) {
#pragma unroll
                for (int jj = 0; jj < 3; ++jj) {
                    int flat = jj * 256 + t;          // 0..767
                    int kb = flat / 192;
                    int n  = flat - kb * 192;
                    int gate = n >> 6, dn = n & 63;
                    const uint4* s = (const uint4*)(wsrc + (size_t)comp * 196608
                                     + ((size_t)(kb0 + kb) * 768 + gate * 256 + dBase + dn) * 8);
                    *(uint4*)&Bs[comp][kb][n][0] = *s;
                }
            }
        }
        __syncthreads();
        // ---- compute ----
        bf16x8 a[2][3];
#pragma unroll
        for (int m = 0; m < 2; ++m) {
            int row = w * 32 + m * 16 + c15;
#pragma unroll
            for (int cc = 0; cc < 3; ++cc)
                a[m][cc] = *(const bf16x8*)&As[cc][q][row][0];
        }
#pragma unroll
        for (int nf = 0; nf < 12; ++nf) {
            int col = nf * 16 + c15;
            bf16x8 bh = *(const bf16x8*)&Bs[0][q][col][0];
            bf16x8 bm = *(const bf16x8*)&Bs[1][q][col][0];
            bf16x8 bl = *(const bf16x8*)&Bs[2][q][col][0];
#pragma unroll
            for (int m = 0; m < 2; ++m) {
                f32x4 acc_ = acc[m][nf];
                acc_ = MFMA(a[m][0], bh, acc_);
                acc_ = MFMA(a[m][1], bh, acc_);
                acc_ = MFMA(a[m][2], bh, acc_);
                acc_ = MFMA(a[m][0], bm, acc_);
                acc_ = MFMA(a[m][1], bm, acc_);
                acc_ = MFMA(a[m][0], bl, acc_);
                acc[m][nf] = acc_;
            }
        }
        __syncthreads();
    }

    // ---- in-register LSTM epilogue ----
#pragma unroll
    for (int m = 0; m < 2; ++m) {
#pragma unroll
        for (int n = 0; n < 4; ++n) {
            int d = dBase + n * 16 + c15;
            float bi = b_iou[d], bo = b_iou[256 + d], bu = b_iou[512 + d];
#pragma unroll
            for (int j = 0; j < 4; ++j) {
                int node = pBase + w * 32 + m * 16 + q * 4 + j;
                if (node < pe) {
                    float ig = acc[m][n][j] + bi;
                    float og = acc[m][n + 4][j] + bo;
                    float ug = acc[m][n + 8][j] + bu;
                    float fcv = 0.f;
                    if (USE_HT && node <= 24999)
                        fcv = fcR[(size_t)(node - ps) * 256 + d];
                    float cn = sigm(ig) * tanhf(ug) + fcv;
                    float hn = sigm(og) * tanhf(cn);
                    cW[(size_t)node * 256 + d] = cn;
                    hW[(size_t)node * 256 + d] = hn;
                }
            }
        }
    }
}

// ---------------------------------------------------------------------------

extern "C" void kernel_launch(void* const* d_in, const int* in_sizes, int n_in,
                              void* d_out, int out_size, void* d_ws, size_t ws_size,
                              hipStream_t stream)
{
    const float* x     = (const float*)d_in[0];
    const float* W_iou = (const float*)d_in[1];
    const float* U_iou = (const float*)d_in[2];
    const float* b_iou = (const float*)d_in[3];
    const float* W_f   = (const float*)d_in[4];
    const float* U_f   = (const float*)d_in[5];
    const float* b_f   = (const float*)d_in[6];

    float* h  = (float*)d_out;                          // N x 256
    float* c  = (float*)d_ws;                           // N x 256
    float* fc = c + (size_t)NN * 256;                   // 20320 x 256
    float* ht = fc + (size_t)20320 * 256;               // 20320 x 256
    ushort_t* wf3   = (ushort_t*)(ht + (size_t)20320 * 256);  // 3 x 65536
    ushort_t* uf3   = wf3   + 3 * 65536;                      // 3 x 65536
    ushort_t* wiou3 = uf3   + 3 * 65536;                      // 3 x 196608
    ushort_t* uiou3 = wiou3 + 3 * 196608;                     // 3 x 196608

    split_weights<<<256, 256, 0, stream>>>(W_f,   wf3,   wf3 + 65536,    wf3 + 2 * 65536,    256, 256);
    split_weights<<<256, 256, 0, stream>>>(U_f,   uf3,   uf3 + 65536,    uf3 + 2 * 65536,    256, 256);
    split_weights<<<768, 256, 0, stream>>>(W_iou, wiou3, wiou3 + 196608, wiou3 + 2 * 196608, 256, 768);
    split_weights<<<768, 256, 0, stream>>>(U_iou, uiou3, uiou3 + 196608, uiou3 + 2 * 196608, 256, 768);

    const int S[8] = {0, 1, 9, 73, 585, 4681, 37449, 200000};

    for (int l = 6; l >= 0; --l) {
        int ps = S[l], pe = S[l + 1], np = pe - ps;
        int pblk = (np + 127) / 128;
        if (l < 6) {
            int cs = S[l + 1], ce = S[l + 2], nch = ce - cs;
            int cblk = (nch + 127) / 128;
            tree_child_mfma<<<dim3(cblk, 2), 256, 0, stream>>>(
                x, wf3, uf3, b_f, c, h, fc, ht, cs, ce, ps);
            tree_parent_mfma<true><<<dim3(pblk, 4), 256, 0, stream>>>(
                x, wiou3, uiou3, b_iou, fc, ht, c, h, ps, pe);
        } else {
            tree_parent_mfma<false><<<dim3(pblk, 4), 256, 0, stream>>>(
                x, wiou3, uiou3, b_iou, nullptr, nullptr, c, h, ps, pe);
        }
    }
}

// Round 3
// 1192.509 us; speedup vs baseline: 2.8361x; 1.2250x over previous
//
#include <hip/hip_runtime.h>
#include <cstddef>
#include <cstdint>

#define NN 200000

typedef _Float16 f16;
typedef __attribute__((ext_vector_type(8))) f16 f16x8;
typedef __attribute__((ext_vector_type(4))) float f32x4;

#define MFMA16(a, b, c) __builtin_amdgcn_mfma_f32_16x16x32_f16((a), (b), (c), 0, 0, 0)

__device__ __forceinline__ float sigm(float v) { return 1.0f / (1.0f + expf(-v)); }

union H8 { uint4 u; f16 f[8]; f16x8 v; };

// fp16 split-2: v = hi + lo/4096 + O(2^-22 |v|); lo scaled into normal range.
__device__ __forceinline__ void split2(float v, f16& hh, f16& ll) {
    hh = (f16)v;
    ll = (f16)((v - (float)hh) * 4096.0f);
}

// bijective XCD-chunking swizzle: dispatch ids on one XCD get contiguous work ids
__device__ __forceinline__ int xcd_swz(int bid, int nwg) {
    int q = nwg >> 3, r = nwg & 7;
    int xcd = bid & 7, i = bid >> 3;
    return (xcd < r ? xcd * (q + 1) : r * (q + 1) + (xcd - r) * q) + i;
}

// ---------------------------------------------------------------------------
// Prep: split x (row-major) and weights (MFMA-frag layout) into fp16 hi/lo
// ---------------------------------------------------------------------------
__global__ void split_x_kernel(const float* __restrict__ src,
                               f16* __restrict__ hi, f16* __restrict__ lo, long n8)
{
    long i = (long)blockIdx.x * blockDim.x + threadIdx.x;
    long stride = (long)gridDim.x * blockDim.x;
    for (; i < n8; i += stride) {
        const float4* s = (const float4*)(src + i * 8);
        float4 a = s[0], b = s[1];
        float vv[8] = {a.x, a.y, a.z, a.w, b.x, b.y, b.z, b.w};
        H8 ph, plv;
#pragma unroll
        for (int j = 0; j < 8; ++j) split2(vv[j], ph.f[j], plv.f[j]);
        *(uint4*)(hi + i * 8) = ph.u;
        *(uint4*)(lo + i * 8) = plv.u;
    }
}

// weight [K][N] fp32 -> frag layout ((k>>3)*N + n)*8 + (k&7), hi/lo fp16
__global__ void split_w_kernel(const float* __restrict__ src,
                               f16* __restrict__ dh, f16* __restrict__ dl, int K, int N)
{
    int e = blockIdx.x * 256 + threadIdx.x;
    if (e >= K * N) return;
    int k = e / N, n = e - k * N;
    f16 hh, ll; split2(src[e], hh, ll);
    int o = ((k >> 3) * N + n) * 8 + (k & 7);
    dh[o] = hh; dl[o] = ll;
}

// ---------------------------------------------------------------------------
// Child kernel: F = sigmoid(x[parent] @ W_f + h @ U_f + b_f), 128 rows x 64 d,
// K=512; epilogue reduces sibling groups -> fc (f32), ht (split f16).
// ---------------------------------------------------------------------------
template<bool PRE>
__launch_bounds__(256, 3)
__global__ void tree_child_mfma(const float* __restrict__ x,
                                const f16* __restrict__ x_hi, const f16* __restrict__ x_lo,
                                const f16* __restrict__ h_hi, const f16* __restrict__ h_lo,
                                const float* __restrict__ hF,
                                const f16* __restrict__ wfh, const f16* __restrict__ wfl,
                                const f16* __restrict__ ufh, const f16* __restrict__ ufl,
                                const float* __restrict__ b_f,
                                const float* __restrict__ cS,
                                float* __restrict__ fc,
                                f16* __restrict__ ht_hi, f16* __restrict__ ht_lo,
                                int cs, int ce, int ps)
{
    __shared__ f16 Ah[4][128][8], Al[4][128][8];   // 16 KB
    __shared__ f16 Bh[4][64][8],  Bl[4][64][8];    //  8 KB

    const int work = xcd_swz(blockIdx.x, gridDim.x);
    const int rt = work >> 2, ct = work & 3;
    const int cBase = cs + rt * 128;
    const int dBase = ct * 64;

    const int t = threadIdx.x;
    const int lane = t & 63, w = t >> 6;
    const int c15 = lane & 15, qq = lane >> 4;
    const int ar = t >> 1;                 // staging row 0..127
    const int aks = (t & 1) << 4;          // k offset 0 / 16

    f32x4 accH[2][4], accL[2][4];
#pragma unroll
    for (int m = 0; m < 2; ++m)
#pragma unroll
        for (int n = 0; n < 4; ++n) { accH[m][n] = (f32x4){0,0,0,0}; accL[m][n] = (f32x4){0,0,0,0}; }

    for (int k0 = 0; k0 < 512; k0 += 32) {
        // ---- stage A: 128 rows x 32 k, hi+lo ----
        int row = cBase + ar;
        uint4 h0 = {0,0,0,0}, h1 = {0,0,0,0}, l0 = {0,0,0,0}, l1 = {0,0,0,0};
        if (row < ce) {
            if (PRE) {
                const f16* ph; const f16* pl;
                if (k0 < 256) {
                    size_t o = (size_t)((row - 1) >> 3) * 256 + k0 + aks;
                    ph = x_hi + o; pl = x_lo + o;
                } else {
                    size_t o = (size_t)row * 256 + (k0 - 256) + aks;
                    ph = h_hi + o; pl = h_lo + o;
                }
                h0 = *(const uint4*)ph;  h1 = *(const uint4*)(ph + 8);
                l0 = *(const uint4*)pl;  l1 = *(const uint4*)(pl + 8);
            } else {
                const float* s = (k0 < 256)
                    ? x  + (size_t)((row - 1) >> 3) * 256 + k0 + aks
                    : hF + (size_t)row * 256 + (k0 - 256) + aks;
                float4 f0 = ((const float4*)s)[0], f1 = ((const float4*)s)[1];
                float4 f2 = ((const float4*)s)[2], f3 = ((const float4*)s)[3];
                float vv[16] = {f0.x,f0.y,f0.z,f0.w, f1.x,f1.y,f1.z,f1.w,
                                f2.x,f2.y,f2.z,f2.w, f3.x,f3.y,f3.z,f3.w};
                H8 a, b, cc, d;
#pragma unroll
                for (int i = 0; i < 8; ++i) { split2(vv[i],     a.f[i],  b.f[i]); }
#pragma unroll
                for (int i = 0; i < 8; ++i) { split2(vv[8 + i], cc.f[i], d.f[i]); }
                h0 = a.u; l0 = b.u; h1 = cc.u; l1 = d.u;
            }
        }
        int kb = aks >> 3;   // 0 or 2
        *(uint4*)&Ah[kb][ar][0]     = h0;
        *(uint4*)&Ah[kb + 1][ar][0] = h1;
        *(uint4*)&Al[kb][ar][0]     = l0;
        *(uint4*)&Al[kb + 1][ar][0] = l1;
        // ---- stage B: 4 kb x 64 cols, hi+lo (1 uint4 each per thread) ----
        {
            const f16* wsh = (k0 < 256) ? wfh : ufh;
            const f16* wsl = (k0 < 256) ? wfl : ufl;
            int kb0 = (k0 & 255) >> 3;
            int kbb = t >> 6, col = t & 63;
            size_t gi = ((size_t)(kb0 + kbb) * 256 + dBase + col) * 8;
            *(uint4*)&Bh[kbb][col][0] = *(const uint4*)(wsh + gi);
            *(uint4*)&Bl[kbb][col][0] = *(const uint4*)(wsl + gi);
        }
        __syncthreads();
        // ---- compute: 3-product emulated fp32 ----
        f16x8 ah[2], al[2];
#pragma unroll
        for (int m = 0; m < 2; ++m) {
            int arow = w * 32 + m * 16 + c15;
            ah[m] = *(const f16x8*)&Ah[qq][arow][0];
            al[m] = *(const f16x8*)&Al[qq][arow][0];
        }
#pragma unroll
        for (int n = 0; n < 4; ++n) {
            int col = n * 16 + c15;
            f16x8 bh = *(const f16x8*)&Bh[qq][col][0];
            f16x8 bl = *(const f16x8*)&Bl[qq][col][0];
#pragma unroll
            for (int m = 0; m < 2; ++m) {
                accH[m][n] = MFMA16(ah[m], bh, accH[m][n]);
                accL[m][n] = MFMA16(ah[m], bl, accL[m][n]);
                accL[m][n] = MFMA16(al[m], bh, accL[m][n]);
            }
        }
        __syncthreads();
    }

    // ---- epilogue: sibling-group reduction ----
    const float INV = 1.0f / 4096.0f;
#pragma unroll
    for (int n = 0; n < 4; ++n) {
        int d = dBase + n * 16 + c15;
        float bfv = b_f[d];
#pragma unroll
        for (int m = 0; m < 2; ++m) {
            float fcs = 0.f, hts = 0.f;
#pragma unroll
            for (int j = 0; j < 4; ++j) {
                int child = cBase + w * 32 + m * 16 + qq * 4 + j;
                if (child < ce) {
                    float val = accH[m][n][j] + accL[m][n][j] * INV;
                    float f = sigm(val + bfv);
                    fcs = fmaf(f, cS[(size_t)child * 256 + d], fcs);
                    hts += hF[(size_t)child * 256 + d];
                }
            }
            fcs += __shfl_xor(fcs, 16);
            hts += __shfl_xor(hts, 16);
            if (!(qq & 1)) {
                int child0 = cBase + w * 32 + m * 16 + (qq >> 1) * 8;
                if (child0 < ce) {
                    int pl_ = ((child0 - 1) >> 3) - ps;
                    size_t o = (size_t)pl_ * 256 + d;
                    fc[o] = fcs;
                    f16 a, b; split2(hts, a, b);
                    ht_hi[o] = a; ht_lo[o] = b;
                }
            }
        }
    }
}

// ---------------------------------------------------------------------------
// Parent kernel: iou = x @ W_iou + ht @ U_iou + b_iou, 64 rows x 192 cols
// (3 gates x 64 d), in-register LSTM epilogue -> c, h (+ split h).
// ---------------------------------------------------------------------------
template<bool PRE, bool USE_HT>
__launch_bounds__(256, 3)
__global__ void tree_parent_mfma(const float* __restrict__ x,
                                 const f16* __restrict__ x_hi, const f16* __restrict__ x_lo,
                                 const f16* __restrict__ wih, const f16* __restrict__ wil,
                                 const f16* __restrict__ uih, const f16* __restrict__ uil,
                                 const float* __restrict__ b_iou,
                                 const float* __restrict__ fcR,
                                 const f16* __restrict__ hth, const f16* __restrict__ htl,
                                 float* __restrict__ cW, float* __restrict__ hW,
                                 f16* __restrict__ h_hi, f16* __restrict__ h_lo,
                                 int ps, int pe)
{
    __shared__ f16 Ah[4][64][8],  Al[4][64][8];    //  8 KB
    __shared__ f16 Bh[4][192][8], Bl[4][192][8];   // 24 KB

    const int work = xcd_swz(blockIdx.x, gridDim.x);
    const int rt = work >> 2, ct = work & 3;
    const int pBase = ps + rt * 64;
    const int dB = ct * 64;                         // d offset within each gate

    const int t = threadIdx.x;
    const int lane = t & 63, w = t >> 6;
    const int c15 = lane & 15, qq = lane >> 4;
    const int ar = t >> 2;                          // staging row 0..63
    const int akb = t & 3;                          // kb 0..3

    f32x4 accH[12], accL[12];
#pragma unroll
    for (int n = 0; n < 12; ++n) { accH[n] = (f32x4){0,0,0,0}; accL[n] = (f32x4){0,0,0,0}; }

    const int KTOT = USE_HT ? 512 : 256;
    for (int k0 = 0; k0 < KTOT; k0 += 32) {
        // ---- stage A: 64 rows x 32 k (1 uint4 per comp per thread) ----
        int row = pBase + ar;
        uint4 hv = {0,0,0,0}, lv = {0,0,0,0};
        if (row < pe) {
            if (k0 < 256) {
                if (PRE) {
                    size_t o = (size_t)row * 256 + k0 + akb * 8;
                    hv = *(const uint4*)(x_hi + o);
                    lv = *(const uint4*)(x_lo + o);
                } else {
                    const float* s = x + (size_t)row * 256 + k0 + akb * 8;
                    float4 f0 = ((const float4*)s)[0], f1 = ((const float4*)s)[1];
                    float vv[8] = {f0.x,f0.y,f0.z,f0.w, f1.x,f1.y,f1.z,f1.w};
                    H8 a, b;
#pragma unroll
                    for (int i = 0; i < 8; ++i) split2(vv[i], a.f[i], b.f[i]);
                    hv = a.u; lv = b.u;
                }
            } else if (USE_HT && row <= 24999) {
                size_t o = (size_t)(row - ps) * 256 + (k0 - 256) + akb * 8;
                hv = *(const uint4*)(hth + o);
                lv = *(const uint4*)(htl + o);
            }
        }
        *(uint4*)&Ah[akb][ar][0] = hv;
        *(uint4*)&Al[akb][ar][0] = lv;
        // ---- stage B: 4 kb x 192 cols (3 uint4 per comp per thread) ----
        {
            const f16* wsh = (k0 < 256) ? wih : uih;
            const f16* wsl = (k0 < 256) ? wil : uil;
            int kb0 = (k0 & 255) >> 3;
#pragma unroll
            for (int j = 0; j < 3; ++j) {
                int flat = j * 256 + t;            // 0..767
                int kbb = flat / 192;
                int col = flat - kbb * 192;
                size_t gi = ((size_t)(kb0 + kbb) * 768 + (col >> 6) * 256 + dB + (col & 63)) * 8;
                *(uint4*)&Bh[kbb][col][0] = *(const uint4*)(wsh + gi);
                *(uint4*)&Bl[kbb][col][0] = *(const uint4*)(wsl + gi);
            }
        }
        __syncthreads();
        // ---- compute ----
        int arow = w * 16 + c15;
        f16x8 ah = *(const f16x8*)&Ah[qq][arow][0];
        f16x8 al = *(const f16x8*)&Al[qq][arow][0];
#pragma unroll
        for (int nf = 0; nf < 12; ++nf) {
            int col = nf * 16 + c15;
            f16x8 bh = *(const f16x8*)&Bh[qq][col][0];
            f16x8 bl = *(const f16x8*)&Bl[qq][col][0];
            accH[nf] = MFMA16(ah, bh, accH[nf]);
            accL[nf] = MFMA16(ah, bl, accL[nf]);
            accL[nf] = MFMA16(al, bh, accL[nf]);
        }
        __syncthreads();
    }

    // ---- in-register LSTM epilogue ----
    const float INV = 1.0f / 4096.0f;
#pragma unroll
    for (int n = 0; n < 4; ++n) {
        int dg = ct * 64 + n * 16 + c15;           // 0..255
        float bi = b_iou[dg], bo = b_iou[256 + dg], bu = b_iou[512 + dg];
#pragma unroll
        for (int j = 0; j < 4; ++j) {
            int node = pBase + w * 16 + qq * 4 + j;
            if (node < pe) {
                float ig = accH[n][j]     + accL[n][j] * INV;
                float og = accH[4 + n][j] + accL[4 + n][j] * INV;
                float ug = accH[8 + n][j] + accL[8 + n][j] * INV;
                float fcv = 0.f;
                if (USE_HT && node <= 24999) fcv = fcR[(size_t)(node - ps) * 256 + dg];
                float cn = sigm(ig) * tanhf(ug) + fcv;
                float hn = sigm(og) * tanhf(cn);
                size_t o = (size_t)node * 256 + dg;
                cW[o] = cn; hW[o] = hn;
                if (PRE) { f16 a, b; split2(hn, a, b); h_hi[o] = a; h_lo[o] = b; }
            }
        }
    }
}

// ---------------------------------------------------------------------------

extern "C" void kernel_launch(void* const* d_in, const int* in_sizes, int n_in,
                              void* d_out, int out_size, void* d_ws, size_t ws_size,
                              hipStream_t stream)
{
    const float* x     = (const float*)d_in[0];
    const float* W_iou = (const float*)d_in[1];
    const float* U_iou = (const float*)d_in[2];
    const float* b_iou = (const float*)d_in[3];
    const float* W_f   = (const float*)d_in[4];
    const float* U_f   = (const float*)d_in[5];
    const float* b_f   = (const float*)d_in[6];

    float* h = (float*)d_out;

    char* p = (char*)d_ws;
    float* c  = (float*)p;  p += (size_t)NN * 256 * 4;
    float* fc = (float*)p;  p += (size_t)20320 * 256 * 4;
    f16* hth = (f16*)p;     p += (size_t)20320 * 256 * 2;
    f16* htl = (f16*)p;     p += (size_t)20320 * 256 * 2;
    f16* wfh = (f16*)p;     p += 65536 * 2;
    f16* wfl = (f16*)p;     p += 65536 * 2;
    f16* ufh = (f16*)p;     p += 65536 * 2;
    f16* ufl = (f16*)p;     p += 65536 * 2;
    f16* wih = (f16*)p;     p += 196608 * 2;
    f16* wil = (f16*)p;     p += 196608 * 2;
    f16* uih = (f16*)p;     p += 196608 * 2;
    f16* uil = (f16*)p;     p += 196608 * 2;
    size_t base_need = (size_t)(p - (char*)d_ws);
    f16* x_hi = (f16*)p;
    f16* x_lo = x_hi + (size_t)NN * 256;
    f16* h_hi = x_lo + (size_t)NN * 256;
    f16* h_lo = h_hi + (size_t)NN * 256;
    size_t full_need = base_need + (size_t)NN * 256 * 2 * 4;
    const bool pre = (ws_size >= full_need);

    split_w_kernel<<<256, 256, 0, stream>>>(W_f,   wfh, wfl, 256, 256);
    split_w_kernel<<<256, 256, 0, stream>>>(U_f,   ufh, ufl, 256, 256);
    split_w_kernel<<<768, 256, 0, stream>>>(W_iou, wih, wil, 256, 768);
    split_w_kernel<<<768, 256, 0, stream>>>(U_iou, uih, uil, 256, 768);
    if (pre)
        split_x_kernel<<<4096, 256, 0, stream>>>(x, x_hi, x_lo, (long)NN * 256 / 8);

    const int S_[8] = {0, 1, 9, 73, 585, 4681, 37449, 200000};

    for (int l = 6; l >= 0; --l) {
        int ps = S_[l], pe = S_[l + 1], np = pe - ps;
        int pgrid = ((np + 63) / 64) * 4;
        if (l == 6) {
            if (pre)
                tree_parent_mfma<true, false><<<pgrid, 256, 0, stream>>>(
                    x, x_hi, x_lo, wih, wil, uih, uil, b_iou,
                    nullptr, nullptr, nullptr, c, h, h_hi, h_lo, ps, pe);
            else
                tree_parent_mfma<false, false><<<pgrid, 256, 0, stream>>>(
                    x, x_hi, x_lo, wih, wil, uih, uil, b_iou,
                    nullptr, nullptr, nullptr, c, h, h_hi, h_lo, ps, pe);
        } else {
            int cs = S_[l + 1], ce = S_[l + 2], nch = ce - cs;
            int cgrid = ((nch + 127) / 128) * 4;
            if (pre) {
                tree_child_mfma<true><<<cgrid, 256, 0, stream>>>(
                    x, x_hi, x_lo, h_hi, h_lo, h, wfh, wfl, ufh, ufl, b_f,
                    c, fc, hth, htl, cs, ce, ps);
                tree_parent_mfma<true, true><<<pgrid, 256, 0, stream>>>(
                    x, x_hi, x_lo, wih, wil, uih, uil, b_iou,
                    fc, hth, htl, c, h, h_hi, h_lo, ps, pe);
            } else {
                tree_child_mfma<false><<<cgrid, 256, 0, stream>>>(
                    x, x_hi, x_lo, h_hi, h_lo, h, wfh, wfl, ufh, ufl, b_f,
                    c, fc, hth, htl, cs, ce, ps);
                tree_parent_mfma<false, true><<<pgrid, 256, 0, stream>>>(
                    x, x_hi, x_lo, wih, wil, uih, uil, b_iou,
                    fc, hth, htl, c, h, h_hi, h_lo, ps, pe);
            }
        }
    }
}